// Round 8
// baseline (246.374 us; speedup 1.0000x reference)
//
#include <hip/hip_runtime.h>
#include <math.h>

#define IN_C 256
#define SE_C 16
#define BATCH 32
#define HW 3136    // 56*56
#define HW4 784    // HW/4 float4s per plane

typedef float f32x4 __attribute__((ext_vector_type(4)));

// ---------------------------------------------------------------------------
// Kernel 1: global average pool. One block per (b,c) plane (8192 blocks).
// Coalesced float4 loads; plain (cached) reads so x stays L3-resident for
// kernel 2 (proven R6: kernel-2 x re-read was 100% L3-hit).
// ---------------------------------------------------------------------------
__global__ __launch_bounds__(256) void se_pool(const float* __restrict__ x,
                                               float* __restrict__ s) {
    const int plane = blockIdx.x;  // b*IN_C + c
    const f32x4* xp = (const f32x4*)(x + (size_t)plane * HW);
    const int t = threadIdx.x;

    float sum = 0.f;
#pragma unroll
    for (int i = 0; i < 3; ++i) {
        f32x4 v = xp[t + i * 256];
        sum += (v.x + v.y) + (v.z + v.w);
    }
    if (t < HW4 - 768) {  // tail: 16 float4
        f32x4 v = xp[768 + t];
        sum += (v.x + v.y) + (v.z + v.w);
    }

    // wave64 butterfly reduce
#pragma unroll
    for (int off = 32; off > 0; off >>= 1) sum += __shfl_down(sum, off);

    __shared__ float wsum[4];
    if ((t & 63) == 0) wsum[t >> 6] = sum;
    __syncthreads();
    if (t == 0) {
        float tot = (wsum[0] + wsum[1]) + (wsum[2] + wsum[3]);
        s[plane] = tot * (1.0f / (float)HW);
    }
}

// ---------------------------------------------------------------------------
// Kernel 2: fused fc + scale, one block per plane (8192 blocks).
// R7 micro-opt: (1) x float4s are PREFETCHED into registers BEFORE the gate
// compute (loads in flight under the FC latency — T14 issue-early);
// (2) gate is computed wave-redundantly with NO LDS and NO __syncthreads:
//     lane = e*4 + i (16 e-groups x 4 lanes), each lane partial-sums 64
//     channels, 2-step shfl reduce within the 4-lane group, then the excite
//     dot pulls h[e] from lane 4*e via __shfl broadcast.
// nt-stores kept (R5 nominal best; out never re-read).
// ---------------------------------------------------------------------------
__global__ __launch_bounds__(256) void se_fcscale(const float* __restrict__ x,
                                                  const float* __restrict__ s,
                                                  const float* __restrict__ w1,
                                                  const float* __restrict__ b1,
                                                  const float* __restrict__ w2,
                                                  const float* __restrict__ b2,
                                                  float* __restrict__ out) {
    const int plane = blockIdx.x;      // b*IN_C + c
    const int b = plane >> 8;          // /IN_C
    const int c = plane & (IN_C - 1);
    const int t = threadIdx.x;

    // ---- (1) prefetch this thread's x slice into registers (issue early) ----
    const f32x4* xp = (const f32x4*)(x + (size_t)plane * HW);
    f32x4 v0 = xp[t];
    f32x4 v1 = xp[t + 256];
    f32x4 v2 = xp[t + 512];
    f32x4 v3 = (t < HW4 - 768) ? xp[768 + t] : f32x4{0.f, 0.f, 0.f, 0.f};

    // ---- (2) wave-redundant gate: lane = e*4 + i over 64 lanes ----
    const int lane = t & 63;
    const int e = lane >> 2;       // 0..15
    const int i = lane & 3;        // 0..3
    const float* srow = s + b * IN_C;
    const float* wrow = w1 + e * IN_C;
    float p = 0.f;
#pragma unroll
    for (int k = 0; k < 64; ++k) {
        const int ch = i + k * 4;  // lanes of a group cover all 256 channels
        p = fmaf(wrow[ch], srow[ch], p);
    }
    // reduce within the 4-lane e-group
    p += __shfl_down(p, 1, 4);
    p += __shfl_down(p, 2, 4);
    // h[e] now valid at lanes where i==0 (lane 4*e)
    const float he = fmaxf(p + b1[e], 0.f);

    // excite dot: broadcast h[e] from lane 4*e to all lanes
    float acc = b2[c];
    const float* w2row = w2 + c * SE_C;
#pragma unroll
    for (int ee = 0; ee < SE_C; ++ee) {
        const float h_ee = __shfl(he, ee * 4);
        acc = fmaf(w2row[ee], h_ee, acc);
    }
    const float gv = 1.0f / (1.0f + expf(-acc));

    // ---- scale the prefetched registers, nontemporal stores ----
    f32x4* op = (f32x4*)(out + (size_t)plane * HW);
    __builtin_nontemporal_store(v0 * gv, &op[t]);
    __builtin_nontemporal_store(v1 * gv, &op[t + 256]);
    __builtin_nontemporal_store(v2 * gv, &op[t + 512]);
    if (t < HW4 - 768) __builtin_nontemporal_store(v3 * gv, &op[768 + t]);
}

extern "C" void kernel_launch(void* const* d_in, const int* in_sizes, int n_in,
                              void* d_out, int out_size, void* d_ws, size_t ws_size,
                              hipStream_t stream) {
    const float* x  = (const float*)d_in[0];
    const float* w1 = (const float*)d_in[1];
    const float* b1 = (const float*)d_in[2];
    const float* w2 = (const float*)d_in[3];
    const float* b2 = (const float*)d_in[4];
    float* out = (float*)d_out;

    float* s = (float*)d_ws;  // 8192 floats (pooled means)

    se_pool<<<BATCH * IN_C, 256, 0, stream>>>(x, s);
    se_fcscale<<<BATCH * IN_C, 256, 0, stream>>>(x, s, w1, b1, w2, b2, out);
}

// Round 14
// 198.767 us; speedup vs baseline: 1.2395x; 1.2395x over previous
//
#include <hip/hip_runtime.h>
#include <math.h>

#define IN_C 256
#define SE_C 16
#define BATCH 32
#define HW 3136    // 56*56
#define HW4 784    // HW/4 float4s per plane

typedef float f32x4 __attribute__((ext_vector_type(4)));

// ---------------------------------------------------------------------------
// Kernel 1: global average pool. One block per (b,c) plane (8192 blocks).
// Each plane = 3136 floats = 784 float4. 256 threads: 3 full float4 rounds
// (768) + 16-thread tail. Coalesced 16B/lane loads -> HBM-read-bound.
// R6 lesson: 8192 independent blocks >> 1024 coop blocks w/ barriers (TLP).
// ---------------------------------------------------------------------------
__global__ __launch_bounds__(256) void se_pool(const float* __restrict__ x,
                                               float* __restrict__ s) {
    const int plane = blockIdx.x;  // b*IN_C + c
    const f32x4* xp = (const f32x4*)(x + (size_t)plane * HW);
    const int t = threadIdx.x;

    float sum = 0.f;
#pragma unroll
    for (int i = 0; i < 3; ++i) {
        f32x4 v = xp[t + i * 256];
        sum += (v.x + v.y) + (v.z + v.w);
    }
    if (t < HW4 - 768) {  // tail: 16 float4
        f32x4 v = xp[768 + t];
        sum += (v.x + v.y) + (v.z + v.w);
    }

    // wave64 butterfly reduce
#pragma unroll
    for (int off = 32; off > 0; off >>= 1) sum += __shfl_down(sum, off);

    __shared__ float wsum[4];
    if ((t & 63) == 0) wsum[t >> 6] = sum;
    __syncthreads();
    if (t == 0) {
        float tot = (wsum[0] + wsum[1]) + (wsum[2] + wsum[3]);
        s[plane] = tot * (1.0f / (float)HW);
    }
}

// ---------------------------------------------------------------------------
// Kernel 2: fused fc + scale. One block per (b,c) plane (8192 blocks).
// R5 structure (best measured: 198.5 µs total) — R8 lesson: keep the gate
// CHEAP per thread (16 FMAs, 16x16 e/i split via LDS) and let block-level
// TLP hide the latency; wave-redundant 64-FMA gate + register prefetch
// made this kernel latency-bound (82.6 µs @ 1.9 TB/s, R8).
//   h[e] = relu(b1[e] + dot(w1[e,:], s[b,:]))   (16x16 thread split + shfl16)
//   gv   = sigmoid(b2[c] + dot(w2[c,:], h))     (wave-uniform, 16 FMAs)
// nt-stores: out never re-read (R5 vs R7 showed nt vs plain = noise).
// ---------------------------------------------------------------------------
__global__ __launch_bounds__(256) void se_fcscale(const float* __restrict__ x,
                                                  const float* __restrict__ s,
                                                  const float* __restrict__ w1,
                                                  const float* __restrict__ b1,
                                                  const float* __restrict__ w2,
                                                  const float* __restrict__ b2,
                                                  float* __restrict__ out) {
    const int plane = blockIdx.x;      // b*IN_C + c
    const int b = plane >> 8;          // /IN_C
    const int c = plane & (IN_C - 1);
    const int t = threadIdx.x;

    __shared__ float hl[SE_C];

    // --- squeeze FC: thread t = e*16 + i; partial over channels i+16k ---
    {
        const int e = t >> 4;
        const int i = t & 15;
        const float* srow = s + b * IN_C;
        const float* wrow = w1 + e * IN_C;
        float p = 0.f;
#pragma unroll
        for (int k = 0; k < 16; ++k) {
            const int ch = i + k * 16;
            p = fmaf(wrow[ch], srow[ch], p);
        }
        // reduce across the 16-lane subgroup (i dimension)
#pragma unroll
        for (int off = 8; off > 0; off >>= 1) p += __shfl_down(p, off, 16);
        if (i == 0) hl[e] = fmaxf(p + b1[e], 0.f);
    }
    __syncthreads();

    // --- excite FC for this plane's channel only (wave-uniform) ---
    float acc = b2[c];
    const float* w2row = w2 + c * SE_C;
#pragma unroll
    for (int e = 0; e < SE_C; ++e) acc = fmaf(w2row[e], hl[e], acc);
    const float gv = 1.0f / (1.0f + expf(-acc));

    // --- scale this plane, nontemporal stores (out never re-read) ---
    const f32x4* xp = (const f32x4*)(x + (size_t)plane * HW);
    f32x4* op = (f32x4*)(out + (size_t)plane * HW);
#pragma unroll
    for (int i = 0; i < 3; ++i) {
        f32x4 v = xp[t + i * 256] * gv;
        __builtin_nontemporal_store(v, &op[t + i * 256]);
    }
    if (t < HW4 - 768) {  // tail: 16 float4
        f32x4 v = xp[768 + t] * gv;
        __builtin_nontemporal_store(v, &op[768 + t]);
    }
}

extern "C" void kernel_launch(void* const* d_in, const int* in_sizes, int n_in,
                              void* d_out, int out_size, void* d_ws, size_t ws_size,
                              hipStream_t stream) {
    const float* x  = (const float*)d_in[0];
    const float* w1 = (const float*)d_in[1];
    const float* b1 = (const float*)d_in[2];
    const float* w2 = (const float*)d_in[3];
    const float* b2 = (const float*)d_in[4];
    float* out = (float*)d_out;

    float* s = (float*)d_ws;  // 8192 floats (pooled means)

    se_pool<<<BATCH * IN_C, 256, 0, stream>>>(x, s);
    se_fcscale<<<BATCH * IN_C, 256, 0, stream>>>(x, s, w1, b1, w2, b2, out);
}